// Round 2
// baseline (4068.430 us; speedup 1.0000x reference)
//
#include <hip/hip_runtime.h>
#include <hip/hip_bf16.h>
#include <math.h>
#include <type_traits>

#define NNODES 100000
#define NEDGES 800000
#define NGRAPH 64
#define NHEAD  4
#define FINALD 512
#define HIDG   64
#define LATD   128

// ---- storage-type load/store helpers (compute always fp32) ----
__device__ __forceinline__ float ldS(const float* p) { return *p; }
__device__ __forceinline__ float ldS(const __hip_bfloat16* p) { return __bfloat162float(*p); }
__device__ __forceinline__ void stS(float* p, float v) { *p = v; }
__device__ __forceinline__ void stS(__hip_bfloat16* p, float v) { *p = __float2bfloat16(v); }

// ---- small utility kernels ----
__global__ void zero_int_kernel(int* p, int n) {
    int i = blockIdx.x * blockDim.x + threadIdx.x;
    if (i < n) p[i] = 0;
}
__global__ void copy_int_kernel(const int* a, int* b, int n) {
    int i = blockIdx.x * blockDim.x + threadIdx.x;
    if (i < n) b[i] = a[i];
}
template <typename TS>
__global__ void convert_kernel(const float* in, TS* out, int n) {
    int i = blockIdx.x * blockDim.x + threadIdx.x;
    if (i < n) stS(&out[i], in[i]);
}

// ---- CSR build: degree count, prefix scan, scatter ----
__global__ void count_kernel(const int* __restrict__ dst, int* __restrict__ deg) {
    int e = blockIdx.x * blockDim.x + threadIdx.x;
    if (e < NEDGES) atomicAdd(&deg[dst[e]], 1);
}

__global__ __launch_bounds__(1024) void scan_kernel(const int* __restrict__ deg,
                                                    int* __restrict__ off) {
    __shared__ int buf[1024];
    __shared__ int carry;
    int t = threadIdx.x;
    if (t == 0) carry = 0;
    __syncthreads();
    for (int base = 0; base < NNODES; base += 1024) {
        int x = (base + t < NNODES) ? deg[base + t] : 0;
        buf[t] = x;
        __syncthreads();
        for (int s = 1; s < 1024; s <<= 1) {
            int v = (t >= s) ? buf[t - s] : 0;
            __syncthreads();
            buf[t] += v;
            __syncthreads();
        }
        if (base + t < NNODES) off[base + t] = carry + buf[t] - x;  // exclusive
        __syncthreads();
        if (t == 1023) carry += buf[1023];
        __syncthreads();
    }
    if (t == 0) off[NNODES] = carry;
}

__global__ void scatter_kernel(const int* __restrict__ dst, int* __restrict__ cursor,
                               int* __restrict__ eidx) {
    int e = blockIdx.x * blockDim.x + threadIdx.x;
    if (e >= NEDGES) return;
    int p = atomicAdd(&cursor[dst[e]], 1);
    eidx[p] = e;
}

// ---- tiled GEMM: C[M,N] = A[M,K] @ B[K,N]; A,C in TS; B fp32; fp32 accumulate ----
template <typename TS>
__global__ __launch_bounds__(256) void sgemm64(const TS* __restrict__ A,
                                               const float* __restrict__ B,
                                               TS* __restrict__ C,
                                               int M, int K, int N) {
    __shared__ float As[16][65];
    __shared__ float Bs[16][65];
    int tid = threadIdx.x;
    int rowBase = blockIdx.x * 64;
    int colBase = blockIdx.y * 64;
    int tr = tid >> 4, tc = tid & 15;
    float acc[4][4] = {{0.f}};
    for (int k0 = 0; k0 < K; k0 += 16) {
#pragma unroll
        for (int i = 0; i < 4; i++) {
            int flat = tid + i * 256;
            int kk = flat & 15, r = flat >> 4;
            int row = rowBase + r, k = k0 + kk;
            As[kk][r] = (row < M && k < K) ? ldS(&A[(size_t)row * K + k]) : 0.f;
        }
#pragma unroll
        for (int i = 0; i < 4; i++) {
            int flat = tid + i * 256;
            int c = flat & 63, kk = flat >> 6;
            int k = k0 + kk;
            Bs[kk][c] = (k < K) ? B[(size_t)k * N + colBase + c] : 0.f;
        }
        __syncthreads();
#pragma unroll
        for (int kk = 0; kk < 16; kk++) {
            float a[4], b[4];
#pragma unroll
            for (int i = 0; i < 4; i++) a[i] = As[kk][tr * 4 + i];
#pragma unroll
            for (int j = 0; j < 4; j++) b[j] = Bs[kk][tc * 4 + j];
#pragma unroll
            for (int i = 0; i < 4; i++)
#pragma unroll
                for (int j = 0; j < 4; j++)
                    acc[i][j] = fmaf(a[i], b[j], acc[i][j]);
        }
        __syncthreads();
    }
#pragma unroll
    for (int i = 0; i < 4; i++) {
        int row = rowBase + tr * 4 + i;
        if (row < M) {
#pragma unroll
            for (int j = 0; j < 4; j++)
                stS(&C[(size_t)row * N + colBase + tc * 4 + j], acc[i][j]);
        }
    }
}

// ---- el/er projections ----
template <typename TS>
__global__ void eler_kernel(const TS* __restrict__ Wh, const float* __restrict__ al,
                            const float* __restrict__ ar, float* __restrict__ el,
                            float* __restrict__ er, int D, int HD) {
    int idx = blockIdx.x * blockDim.x + threadIdx.x;
    if (idx >= NNODES * NHEAD) return;
    int n = idx >> 2, h = idx & 3;
    const TS* w = Wh + (size_t)n * HD + h * D;
    const float* a = al + h * D;
    const float* b = ar + h * D;
    float sl = 0.f, sr = 0.f;
    for (int d = 0; d < D; d++) {
        float v = ldS(&w[d]);
        sl = fmaf(v, a[d], sl);
        sr = fmaf(v, b[d], sr);
    }
    el[idx] = sl;
    er[idx] = sr;
}

// ---- per-(node,head) edge softmax over CSR in-edges; writes normalized weights ----
__global__ void attn_kernel(const int* __restrict__ src, const int* __restrict__ eidx,
                            const int* __restrict__ off, const float* __restrict__ el,
                            const float* __restrict__ er, float* __restrict__ aw) {
    int idx = blockIdx.x * blockDim.x + threadIdx.x;
    if (idx >= NNODES * NHEAD) return;
    int n = idx >> 2, h = idx & 3;
    int i0 = off[n], i1 = off[n + 1];
    if (i0 == i1) return;
    float ern = er[n * 4 + h];
    float m = -1e30f;
    for (int i = i0; i < i1; i++) {
        float x = el[src[eidx[i]] * 4 + h] + ern;
        x = (x >= 0.f) ? x : 0.2f * x;
        m = fmaxf(m, x);
    }
    float s = 0.f;
    for (int i = i0; i < i1; i++) {
        int e = eidx[i];
        float x = el[src[e] * 4 + h] + ern;
        x = (x >= 0.f) ? x : 0.2f * x;
        float v = expf(x - m);
        aw[e * 4 + h] = v;
        s += v;
    }
    float inv = 1.f / fmaxf(s, 1e-9f);
    for (int i = i0; i < i1; i++) aw[eidx[i] * 4 + h] *= inv;
}

// ---- gather-aggregate + bias + ELU (no atomics) ----
template <typename TS>
__global__ void aggregate_kernel(const int* __restrict__ src, const int* __restrict__ eidx,
                                 const int* __restrict__ off, const TS* __restrict__ Wh,
                                 const float* __restrict__ aw, const float* __restrict__ bias,
                                 TS* __restrict__ out, int HD, int logHD, int logD, int total) {
    int idx = blockIdx.x * blockDim.x + threadIdx.x;
    if (idx >= total) return;
    int n = idx >> logHD;
    int d = idx & (HD - 1);
    int h = d >> logD;
    float acc = 0.f;
    int i0 = off[n], i1 = off[n + 1];
    for (int i = i0; i < i1; i++) {
        int e = eidx[i];
        acc += aw[e * 4 + h] * ldS(&Wh[(size_t)src[e] * HD + d]);
    }
    float x = acc + bias[d];
    stS(&out[(size_t)n * HD + d], (x > 0.f) ? x : (expf(x) - 1.f));
}

// ---- gate MLP: one wave per node ----
template <typename TS>
__global__ __launch_bounds__(64) void gate_kernel(const TS* __restrict__ h,
                                                  const float* __restrict__ Wg1,
                                                  const float* __restrict__ bg1,
                                                  const float* __restrict__ Wg2,
                                                  const float* __restrict__ bg2,
                                                  float* __restrict__ gate) {
    int n = blockIdx.x;
    int t = threadIdx.x;
    const TS* row = h + (size_t)n * FINALD;
    float acc = bg1[t];
    for (int k = 0; k < FINALD; k++)
        acc = fmaf(ldS(&row[k]), Wg1[k * HIDG + t], acc);
    acc = fmaxf(acc, 0.f) * Wg2[t];
#pragma unroll
    for (int o = 32; o > 0; o >>= 1)
        acc += __shfl_down(acc, o, 64);
    if (t == 0) gate[n] = acc + bg2[0];
}

// ---- graph boundaries via binary search on sorted graph_id ----
__global__ void gstart_kernel(const int* __restrict__ gid, int* __restrict__ gstart) {
    int g = blockIdx.x * blockDim.x + threadIdx.x;
    if (g > NGRAPH) return;
    int lo = 0, hi = NNODES;
    while (lo < hi) {
        int mid = (lo + hi) >> 1;
        if (gid[mid] < g) lo = mid + 1; else hi = mid;
    }
    gstart[g] = lo;
}

// ---- per-graph softmax over node gates (block per graph) ----
__global__ __launch_bounds__(256) void graph_softmax_kernel(const float* __restrict__ gate,
                                                            const int* __restrict__ gstart,
                                                            float* __restrict__ exn,
                                                            float* __restrict__ gsum) {
    int g = blockIdx.x, t = threadIdx.x;
    int n0 = gstart[g], n1 = gstart[g + 1];
    __shared__ float red[256];
    float m = -1e30f;
    for (int n = n0 + t; n < n1; n += 256) m = fmaxf(m, gate[n]);
    red[t] = m; __syncthreads();
    for (int s = 128; s > 0; s >>= 1) {
        if (t < s) red[t] = fmaxf(red[t], red[t + s]);
        __syncthreads();
    }
    m = red[0]; __syncthreads();
    float sum = 0.f;
    for (int n = n0 + t; n < n1; n += 256) {
        float v = expf(gate[n] - m);
        exn[n] = v;
        sum += v;
    }
    red[t] = sum; __syncthreads();
    for (int s = 128; s > 0; s >>= 1) {
        if (t < s) red[t] += red[t + s];
        __syncthreads();
    }
    if (t == 0) gsum[g] = red[0];
}

// ---- pooled[g,d] = sum_n exn[n]*h[n,d] (unnormalized; denom folded into final) ----
template <typename TS>
__global__ __launch_bounds__(128) void pool_kernel(const TS* __restrict__ h,
                                                   const float* __restrict__ exn,
                                                   const int* __restrict__ gstart,
                                                   float* __restrict__ pooled) {
    int g = blockIdx.x;
    int d = blockIdx.y * 128 + threadIdx.x;
    int n0 = gstart[g], n1 = gstart[g + 1];
    float acc = 0.f;
    for (int n = n0; n < n1; n++)
        acc += exn[n] * ldS(&h[(size_t)n * FINALD + d]);
    pooled[g * FINALD + d] = acc;
}

// ---- mu/logvar = (pooled/denom) @ W + b ----
__global__ __launch_bounds__(128) void final_kernel(const float* __restrict__ pooled,
                                                    const float* __restrict__ gsum,
                                                    const float* __restrict__ Wmu,
                                                    const float* __restrict__ bmu,
                                                    const float* __restrict__ Wlv,
                                                    const float* __restrict__ blv,
                                                    float* __restrict__ out) {
    int g = blockIdx.x, j = threadIdx.x;
    const float* p = pooled + g * FINALD;
    float am = 0.f, av = 0.f;
    for (int k = 0; k < FINALD; k++) {
        float pv = p[k];
        am = fmaf(pv, Wmu[k * LATD + j], am);
        av = fmaf(pv, Wlv[k * LATD + j], av);
    }
    float inv = 1.f / fmaxf(gsum[g], 1e-9f);
    out[g * LATD + j] = am * inv + bmu[j];
    out[NGRAPH * LATD + g * LATD + j] = av * inv + blv[j];
}

// ======================= pipeline driver (templated on storage type) ==================
template <typename TS>
static void run_all(void* const* d_in, void* d_out, void* d_ws, hipStream_t stream) {
    const float* node_feat = (const float*)d_in[0];
    const int* src = (const int*)d_in[1];
    const int* dst = (const int*)d_in[2];
    const int* gid = (const int*)d_in[3];
    const float* W[3]    = {(const float*)d_in[4],  (const float*)d_in[8],  (const float*)d_in[12]};
    const float* al[3]   = {(const float*)d_in[5],  (const float*)d_in[9],  (const float*)d_in[13]};
    const float* ar[3]   = {(const float*)d_in[6],  (const float*)d_in[10], (const float*)d_in[14]};
    const float* bias[3] = {(const float*)d_in[7],  (const float*)d_in[11], (const float*)d_in[15]};
    const float* Wg1 = (const float*)d_in[16];
    const float* bg1 = (const float*)d_in[17];
    const float* Wg2 = (const float*)d_in[18];
    const float* bg2 = (const float*)d_in[19];
    const float* Wmu = (const float*)d_in[20];
    const float* bmu = (const float*)d_in[21];
    const float* Wlv = (const float*)d_in[22];
    const float* blv = (const float*)d_in[23];

    char* ws = (char*)d_ws;
    size_t woff = 0;
    auto carve = [&](size_t bytes) {
        void* p = ws + woff;
        woff = (woff + bytes + 255) & ~(size_t)255;
        return p;
    };
    TS*       hA     = (TS*)      carve((size_t)NNODES * 512 * sizeof(TS));
    TS*       hB     = (TS*)      carve((size_t)NNODES * 512 * sizeof(TS));
    TS*       x0     = (TS*)      carve((size_t)NNODES * 92 * sizeof(TS));
    float*    el     = (float*)   carve((size_t)NNODES * 4 * 4);
    float*    er     = (float*)   carve((size_t)NNODES * 4 * 4);
    float*    aw     = (float*)   carve((size_t)NEDGES * 4 * 4);
    int*      deg    = (int*)     carve((size_t)NNODES * 4);
    int*      off    = (int*)     carve((size_t)(NNODES + 1) * 4);
    int*      cursor = (int*)     carve((size_t)NNODES * 4);
    int*      eidx   = (int*)     carve((size_t)NEDGES * 4);
    float*    gate   = (float*)   carve((size_t)NNODES * 4);
    float*    exn    = (float*)   carve((size_t)NNODES * 4);
    int*      gstart = (int*)     carve((size_t)(NGRAPH + 1) * 4);
    float*    pooled = (float*)   carve((size_t)NGRAPH * FINALD * 4);
    float*    gsum   = (float*)   carve((size_t)NGRAPH * 4);

    // ---- CSR build (per launch; deterministic result, order within node arbitrary) ----
    zero_int_kernel<<<(NNODES + 255) / 256, 256, 0, stream>>>(deg, NNODES);
    count_kernel<<<(NEDGES + 255) / 256, 256, 0, stream>>>(dst, deg);
    scan_kernel<<<1, 1024, 0, stream>>>(deg, off);
    copy_int_kernel<<<(NNODES + 255) / 256, 256, 0, stream>>>(off, cursor, NNODES);
    scatter_kernel<<<(NEDGES + 255) / 256, 256, 0, stream>>>(dst, cursor, eidx);
    gstart_kernel<<<1, 128, 0, stream>>>(gid, gstart);

    // ---- input conversion ----
    const TS* hin;
    if constexpr (std::is_same_v<TS, float>) {
        hin = (const TS*)node_feat;
    } else {
        convert_kernel<TS><<<(NNODES * 92 + 255) / 256, 256, 0, stream>>>(node_feat, x0, NNODES * 92);
        hin = x0;
    }

    const int Kdim[3]  = {92, 128, 256};
    const int HDs[3]   = {128, 256, 512};
    const int logHD[3] = {7, 8, 9};
    const int logD[3]  = {5, 6, 7};

    for (int l = 0; l < 3; l++) {
        int K = Kdim[l], HD = HDs[l], D = HD / NHEAD;
        dim3 ggrid((NNODES + 63) / 64, HD / 64);
        sgemm64<TS><<<ggrid, 256, 0, stream>>>(hin, W[l], hB, NNODES, K, HD);
        eler_kernel<TS><<<(NNODES * NHEAD + 255) / 256, 256, 0, stream>>>(hB, al[l], ar[l], el, er, D, HD);
        attn_kernel<<<(NNODES * NHEAD + 255) / 256, 256, 0, stream>>>(src, eidx, off, el, er, aw);
        int total = NNODES * HD;
        aggregate_kernel<TS><<<(total + 255) / 256, 256, 0, stream>>>(
            src, eidx, off, hB, aw, bias[l], hA, HD, logHD[l], logD[l], total);
        hin = hA;
    }

    // ---- attention pooling ----
    gate_kernel<TS><<<NNODES, 64, 0, stream>>>(hA, Wg1, bg1, Wg2, bg2, gate);
    graph_softmax_kernel<<<NGRAPH, 256, 0, stream>>>(gate, gstart, exn, gsum);
    pool_kernel<TS><<<dim3(NGRAPH, FINALD / 128), 128, 0, stream>>>(hA, exn, gstart, pooled);
    final_kernel<<<NGRAPH, 128, 0, stream>>>(pooled, gsum, Wmu, bmu, Wlv, blv, (float*)d_out);
}

extern "C" void kernel_launch(void* const* d_in, const int* in_sizes, int n_in,
                              void* d_out, int out_size, void* d_ws, size_t ws_size,
                              hipStream_t stream) {
    (void)in_sizes; (void)n_in; (void)out_size;
    // fp32 layout needs ~468 MB; bf16-storage layout needs ~245 MB.
    if (ws_size >= (size_t)480 * 1024 * 1024) {
        run_all<float>(d_in, d_out, d_ws, stream);
    } else {
        run_all<__hip_bfloat16>(d_in, d_out, d_ws, stream);
    }
}

// Round 4
// 1467.447 us; speedup vs baseline: 2.7725x; 2.7725x over previous
//
#include <hip/hip_runtime.h>
#include <math.h>

#define NNODES 100000
#define NEDGES 800000
#define NGRAPH 64
#define NHEAD  4
#define FINALD 512
#define HIDG   64
#define LATD   128
#define NB_SCAN 98  // ceil(NNODES/1024)

typedef unsigned int uint;
typedef unsigned short ushort;

// ---- bf16 helpers (buffers are ushort; fp32<->bf16 by bit ops, RNE pack) ----
__device__ __forceinline__ float bflo(uint u) { return __uint_as_float(u << 16); }
__device__ __forceinline__ float bfhi(uint u) { return __uint_as_float(u & 0xffff0000u); }
__device__ __forceinline__ float bf2f(ushort s) { return __uint_as_float((uint)s << 16); }
__device__ __forceinline__ ushort f2bf(float f) {
    uint u = __float_as_uint(f);
    return (ushort)((u + 0x7fffu + ((u >> 16) & 1u)) >> 16);
}
__device__ __forceinline__ uint pack2(float a, float b) {
    return (uint)f2bf(a) | ((uint)f2bf(b) << 16);
}
// generic scalar loads
__device__ __forceinline__ float ldS(const float* p) { return *p; }
__device__ __forceinline__ float ldS(const ushort* p) { return bf2f(*p); }
// 4-wide A loads for GEMM staging
__device__ __forceinline__ void loadA4(const float* p, float* v) {
    float4 t = *(const float4*)p;
    v[0] = t.x; v[1] = t.y; v[2] = t.z; v[3] = t.w;
}
__device__ __forceinline__ void loadA4(const ushort* p, float* v) {
    uint2 t = *(const uint2*)p;
    v[0] = bflo(t.x); v[1] = bfhi(t.x); v[2] = bflo(t.y); v[3] = bfhi(t.y);
}
// 4-wide C stores
__device__ __forceinline__ void storeC4(float* p, const float* v) {
    *(float4*)p = make_float4(v[0], v[1], v[2], v[3]);
}
__device__ __forceinline__ void storeC4(ushort* p, const float* v) {
    uint2 t;
    t.x = pack2(v[0], v[1]);
    t.y = pack2(v[2], v[3]);
    *(uint2*)p = t;
}

// ======================== CSR build ========================
__global__ void zero_int_kernel(int* p, int n) {
    int i = blockIdx.x * blockDim.x + threadIdx.x;
    if (i < n) p[i] = 0;
}
__global__ void copy_int_kernel(const int* a, int* b, int n) {
    int i = blockIdx.x * blockDim.x + threadIdx.x;
    if (i < n) b[i] = a[i];
}
__global__ void count_kernel(const int* __restrict__ dst, int* __restrict__ deg) {
    int e = blockIdx.x * blockDim.x + threadIdx.x;
    if (e < NEDGES) atomicAdd(&deg[dst[e]], 1);
}
__global__ __launch_bounds__(1024) void scan_block_kernel(const int* __restrict__ deg,
                                                          int* __restrict__ off,
                                                          int* __restrict__ bsum) {
    __shared__ int buf[1024];
    int t = threadIdx.x;
    int i = blockIdx.x * 1024 + t;
    int x = (i < NNODES) ? deg[i] : 0;
    buf[t] = x;
    __syncthreads();
    for (int s = 1; s < 1024; s <<= 1) {
        int v = (t >= s) ? buf[t - s] : 0;
        __syncthreads();
        buf[t] += v;
        __syncthreads();
    }
    if (i < NNODES) off[i] = buf[t] - x;  // exclusive within block
    if (t == 1023) bsum[blockIdx.x] = buf[1023];
}
__global__ __launch_bounds__(128) void scan_bsum_kernel(int* __restrict__ bsum) {
    __shared__ int buf[128];
    int t = threadIdx.x;
    int x = (t < NB_SCAN) ? bsum[t] : 0;
    buf[t] = x;
    __syncthreads();
    for (int s = 1; s < 128; s <<= 1) {
        int v = (t >= s) ? buf[t - s] : 0;
        __syncthreads();
        buf[t] += v;
        __syncthreads();
    }
    if (t < NB_SCAN) bsum[t] = buf[t] - x;
    if (t == 0) bsum[NB_SCAN] = buf[NB_SCAN - 1];
}
__global__ __launch_bounds__(1024) void scan_add_kernel(int* __restrict__ off,
                                                        const int* __restrict__ bsum) {
    int i = blockIdx.x * 1024 + threadIdx.x;
    if (i < NNODES) off[i] += bsum[blockIdx.x];
    if (i == 0) off[NNODES] = bsum[NB_SCAN];
}
__global__ void scatter_kernel(const int* __restrict__ src, const int* __restrict__ dst,
                               int* __restrict__ cursor, int* __restrict__ src_csr) {
    int e = blockIdx.x * blockDim.x + threadIdx.x;
    if (e >= NEDGES) return;
    int p = atomicAdd(&cursor[dst[e]], 1);
    src_csr[p] = src[e];
}
__global__ void gstart_kernel(const int* __restrict__ gid, int* __restrict__ gstart) {
    int g = blockIdx.x * blockDim.x + threadIdx.x;
    if (g > NGRAPH) return;
    int lo = 0, hi = NNODES;
    while (lo < hi) {
        int mid = (lo + hi) >> 1;
        if (gid[mid] < g) lo = mid + 1; else hi = mid;
    }
    gstart[g] = lo;
}

// ======================== SGEMM: C[M,N] = A[M,K] @ B[K,N] ========================
// A: TA (fp32 or bf16), B: fp32 weights, C: TC (bf16 or fp32). fp32 accumulate.
template <typename TA, typename TC, int BN, bool RELU>
__global__ __launch_bounds__(256) void sgemm_tile(const TA* __restrict__ A,
                                                  const float* __restrict__ B,
                                                  const float* __restrict__ bias,
                                                  TC* __restrict__ C,
                                                  int M, int K, int N) {
    constexpr int CW = (BN == 128) ? 8 : 4;
    __shared__ float As[16][132];
    __shared__ float Bs[16][BN + 4];
    int tid = threadIdx.x;
    int rowBase = blockIdx.x * 128;
    int colBase = blockIdx.y * BN;
    int tx = tid & 15, ty = tid >> 4;
    float acc[8][CW];
#pragma unroll
    for (int i = 0; i < 8; i++)
#pragma unroll
        for (int j = 0; j < CW; j++) acc[i][j] = 0.f;

    for (int k0 = 0; k0 < K; k0 += 16) {
        bool fullk = (k0 + 16 <= K);
        // stage A (128 rows x 16 k) transposed into As[k][row]
#pragma unroll
        for (int i = 0; i < 2; i++) {
            int r = (tid >> 2) + i * 64;
            int kq = (tid & 3) * 4;
            int row = rowBase + r;
            float v[4] = {0.f, 0.f, 0.f, 0.f};
            if (row < M) {
                if (fullk) {
                    loadA4(&A[(size_t)row * K + k0 + kq], v);
                } else {
#pragma unroll
                    for (int j = 0; j < 4; j++) {
                        int k = k0 + kq + j;
                        if (k < K) v[j] = ldS(&A[(size_t)row * K + k]);
                    }
                }
            }
            As[kq + 0][r] = v[0];
            As[kq + 1][r] = v[1];
            As[kq + 2][r] = v[2];
            As[kq + 3][r] = v[3];
        }
        // stage B (16 k x BN cols)
        {
            int kk = tid >> 4;
            int k = k0 + kk;
            constexpr int PER = BN / 16;
            int cq = (tid & 15) * PER;
#pragma unroll
            for (int c = 0; c < PER; c += 4) {
                float4 v = make_float4(0.f, 0.f, 0.f, 0.f);
                if (k < K) v = *(const float4*)&B[(size_t)k * N + colBase + cq + c];
                *(float4*)&Bs[kk][cq + c] = v;
            }
        }
        __syncthreads();
#pragma unroll
        for (int kk = 0; kk < 16; kk++) {
            float a[8], b[CW];
            *(float4*)&a[0] = *(const float4*)&As[kk][ty * 4];
            *(float4*)&a[4] = *(const float4*)&As[kk][64 + ty * 4];
            *(float4*)&b[0] = *(const float4*)&Bs[kk][tx * 4];
            if constexpr (CW == 8) *(float4*)&b[4] = *(const float4*)&Bs[kk][64 + tx * 4];
#pragma unroll
            for (int i = 0; i < 8; i++)
#pragma unroll
                for (int j = 0; j < CW; j++)
                    acc[i][j] = fmaf(a[i], b[j], acc[i][j]);
        }
        __syncthreads();
    }
    float bb[CW];
    if constexpr (RELU) {
#pragma unroll
        for (int half = 0; half < CW / 4; half++)
            *(float4*)&bb[half * 4] = *(const float4*)&bias[colBase + half * 64 + tx * 4];
    }
#pragma unroll
    for (int i = 0; i < 8; i++) {
        int r = rowBase + ((i < 4) ? (ty * 4 + i) : (64 + ty * 4 + i - 4));
        if (r < M) {
#pragma unroll
            for (int half = 0; half < CW / 4; half++) {
                float v[4];
#pragma unroll
                for (int j = 0; j < 4; j++) {
                    float x = acc[i][half * 4 + j];
                    if constexpr (RELU) x = fmaxf(x + bb[half * 4 + j], 0.f);
                    v[j] = x;
                }
                storeC4(&C[(size_t)r * N + colBase + half * 64 + tx * 4], v);
            }
        }
    }
}

// ======================== el/er: one wave per (node, head); Wh bf16 ========================
__global__ __launch_bounds__(256) void eler_wave(const ushort* __restrict__ Wh,
                                                 const float* __restrict__ al,
                                                 const float* __restrict__ ar,
                                                 float* __restrict__ el,
                                                 float* __restrict__ er,
                                                 int D, int HD) {
    int n = blockIdx.x;
    int h = threadIdx.x >> 6;
    int lane = threadIdx.x & 63;
    const ushort* w = Wh + (size_t)n * HD + h * D;
    const float* pa = al + h * D;
    const float* pb = ar + h * D;
    float sl = 0.f, sr = 0.f;
    if (lane < D) {
        float v = bf2f(w[lane]);
        sl = v * pa[lane];
        sr = v * pb[lane];
    }
    if (D == 128) {
        float v = bf2f(w[lane + 64]);
        sl = fmaf(v, pa[lane + 64], sl);
        sr = fmaf(v, pb[lane + 64], sr);
    }
#pragma unroll
    for (int o = 32; o > 0; o >>= 1) {
        sl += __shfl_down(sl, o, 64);
        sr += __shfl_down(sr, o, 64);
    }
    if (lane == 0) {
        el[n * 4 + h] = sl;
        er[n * 4 + h] = sr;
    }
}

// ======================== edge softmax over CSR in-edges ========================
__global__ void attn_softmax(const int* __restrict__ src_csr, const int* __restrict__ off,
                             const float* __restrict__ el, const float* __restrict__ er,
                             float* __restrict__ aw) {
    int idx = blockIdx.x * blockDim.x + threadIdx.x;
    if (idx >= NNODES * NHEAD) return;
    int n = idx >> 2, h = idx & 3;
    int i0 = off[n], i1 = off[n + 1];
    if (i0 == i1) return;
    float ern = er[n * 4 + h];
    float m = -1e30f;
    for (int i = i0; i < i1; i += 8) {
        int cnt = i1 - i; if (cnt > 8) cnt = 8;
        int s8[8];
#pragma unroll
        for (int j = 0; j < 8; j++)
            if (j < cnt) s8[j] = src_csr[i + j];
#pragma unroll
        for (int j = 0; j < 8; j++) {
            if (j < cnt) {
                float x = el[s8[j] * 4 + h] + ern;
                x = (x >= 0.f) ? x : 0.2f * x;
                aw[(i + j) * 4 + h] = x;
                m = fmaxf(m, x);
            }
        }
    }
    float s = 0.f;
    for (int i = i0; i < i1; i++) {
        float v = expf(aw[i * 4 + h] - m);
        aw[i * 4 + h] = v;
        s += v;
    }
    float inv = 1.f / fmaxf(s, 1e-9f);
    for (int i = i0; i < i1; i++) aw[i * 4 + h] *= inv;
}

// ======================== aggregate: 8 bf16 dims/thread, batched prefetch ========================
__global__ __launch_bounds__(256) void gat_aggregate(const int* __restrict__ src_csr,
                                                     const int* __restrict__ off,
                                                     const ushort* __restrict__ Wh,
                                                     const float* __restrict__ aw,
                                                     const float* __restrict__ bias,
                                                     ushort* __restrict__ out,
                                                     int HD, int logHD8, int logD, int total8) {
    int idx = blockIdx.x * blockDim.x + threadIdx.x;
    if (idx >= total8) return;
    int n = idx >> logHD8;
    int d = (idx & ((1 << logHD8) - 1)) << 3;  // 8 dims per thread
    int h = d >> logD;
    int i0 = off[n], i1 = off[n + 1];
    float acc[8] = {0.f, 0.f, 0.f, 0.f, 0.f, 0.f, 0.f, 0.f};
    for (int i = i0; i < i1; i += 8) {
        int cnt = i1 - i; if (cnt > 8) cnt = 8;
        int s8[8]; float w8[8];
#pragma unroll
        for (int j = 0; j < 8; j++) {
            if (j < cnt) {
                s8[j] = src_csr[i + j];
                w8[j] = aw[(i + j) * 4 + h];
            }
        }
#pragma unroll
        for (int j = 0; j < 8; j++) {
            if (j < cnt) {
                uint4 v = *(const uint4*)&Wh[(size_t)s8[j] * HD + d];
                float w = w8[j];
                acc[0] = fmaf(w, bflo(v.x), acc[0]);
                acc[1] = fmaf(w, bfhi(v.x), acc[1]);
                acc[2] = fmaf(w, bflo(v.y), acc[2]);
                acc[3] = fmaf(w, bfhi(v.y), acc[3]);
                acc[4] = fmaf(w, bflo(v.z), acc[4]);
                acc[5] = fmaf(w, bfhi(v.z), acc[5]);
                acc[6] = fmaf(w, bflo(v.w), acc[6]);
                acc[7] = fmaf(w, bfhi(v.w), acc[7]);
            }
        }
    }
    uint4 o;
    float r[8];
#pragma unroll
    for (int j = 0; j < 8; j++) {
        float x = acc[j] + bias[d + j];
        r[j] = (x > 0.f) ? x : (expf(x) - 1.f);
    }
    o.x = pack2(r[0], r[1]);
    o.y = pack2(r[2], r[3]);
    o.z = pack2(r[4], r[5]);
    o.w = pack2(r[6], r[7]);
    *(uint4*)&out[(size_t)n * HD + d] = o;
}

// ======================== gate: hg @ Wg2 + bg2 (one wave per node) ========================
__global__ __launch_bounds__(256) void gate_dot(const float* __restrict__ hg,
                                                const float* __restrict__ Wg2,
                                                const float* __restrict__ bg2,
                                                float* __restrict__ gate) {
    int n = blockIdx.x * 4 + (threadIdx.x >> 6);
    int lane = threadIdx.x & 63;
    float v = hg[(size_t)n * HIDG + lane] * Wg2[lane];
#pragma unroll
    for (int o = 32; o > 0; o >>= 1)
        v += __shfl_down(v, o, 64);
    if (lane == 0) gate[n] = v + bg2[0];
}

// ======================== per-graph softmax over node gates ========================
__global__ __launch_bounds__(256) void graph_softmax_kernel(const float* __restrict__ gate,
                                                            const int* __restrict__ gstart,
                                                            float* __restrict__ exn,
                                                            float* __restrict__ gsum) {
    int g = blockIdx.x, t = threadIdx.x;
    int n0 = gstart[g], n1 = gstart[g + 1];
    __shared__ float red[256];
    float m = -1e30f;
    for (int n = n0 + t; n < n1; n += 256) m = fmaxf(m, gate[n]);
    red[t] = m; __syncthreads();
    for (int s = 128; s > 0; s >>= 1) {
        if (t < s) red[t] = fmaxf(red[t], red[t + s]);
        __syncthreads();
    }
    m = red[0]; __syncthreads();
    float sum = 0.f;
    for (int n = n0 + t; n < n1; n += 256) {
        float v = expf(gate[n] - m);
        exn[n] = v;
        sum += v;
    }
    red[t] = sum; __syncthreads();
    for (int s = 128; s > 0; s >>= 1) {
        if (t < s) red[t] += red[t + s];
        __syncthreads();
    }
    if (t == 0) gsum[g] = red[0];
}

// ======================== pooled partial sums (4 blocks per graph); h bf16 ========================
__global__ __launch_bounds__(128) void pool_partial(const ushort* __restrict__ h,
                                                    const float* __restrict__ exn,
                                                    const int* __restrict__ gstart,
                                                    float* __restrict__ partial) {
    int g = blockIdx.x, q = blockIdx.y;
    int n0 = gstart[g], n1 = gstart[g + 1];
    int len = n1 - n0;
    int chunk = (len + 3) >> 2;
    int s = n0 + q * chunk;
    int e = s + chunk; if (e > n1) e = n1;
    int d4 = threadIdx.x;  // handles dims 4*d4 .. 4*d4+3
    const uint2* h2 = (const uint2*)h;
    float a0 = 0.f, a1 = 0.f, a2 = 0.f, a3 = 0.f;
    for (int n = s; n < e; n++) {
        float w = exn[n];
        uint2 v = h2[(size_t)n * 128 + d4];
        a0 = fmaf(w, bflo(v.x), a0);
        a1 = fmaf(w, bfhi(v.x), a1);
        a2 = fmaf(w, bflo(v.y), a2);
        a3 = fmaf(w, bfhi(v.y), a3);
    }
    *(float4*)&partial[((size_t)(g * 4 + q)) * FINALD + d4 * 4] = make_float4(a0, a1, a2, a3);
}

// ======================== final heads ========================
__global__ __launch_bounds__(128) void final_kernel(const float* __restrict__ partial,
                                                    const float* __restrict__ gsum,
                                                    const float* __restrict__ Wmu,
                                                    const float* __restrict__ bmu,
                                                    const float* __restrict__ Wlv,
                                                    const float* __restrict__ blv,
                                                    float* __restrict__ out) {
    int g = blockIdx.x, j = threadIdx.x;
    const float* p = partial + (size_t)g * 4 * FINALD;
    float am = 0.f, av = 0.f;
    for (int k = 0; k < FINALD; k++) {
        float pv = p[k] + p[FINALD + k] + p[2 * FINALD + k] + p[3 * FINALD + k];
        am = fmaf(pv, Wmu[k * LATD + j], am);
        av = fmaf(pv, Wlv[k * LATD + j], av);
    }
    float inv = 1.f / fmaxf(gsum[g], 1e-9f);
    out[g * LATD + j] = am * inv + bmu[j];
    out[NGRAPH * LATD + g * LATD + j] = av * inv + blv[j];
}

// ======================== driver ========================
extern "C" void kernel_launch(void* const* d_in, const int* in_sizes, int n_in,
                              void* d_out, int out_size, void* d_ws, size_t ws_size,
                              hipStream_t stream) {
    (void)in_sizes; (void)n_in; (void)out_size; (void)ws_size;
    const float* node_feat = (const float*)d_in[0];
    const int* src = (const int*)d_in[1];
    const int* dst = (const int*)d_in[2];
    const int* gid = (const int*)d_in[3];
    const float* W[3]    = {(const float*)d_in[4],  (const float*)d_in[8],  (const float*)d_in[12]};
    const float* al[3]   = {(const float*)d_in[5],  (const float*)d_in[9],  (const float*)d_in[13]};
    const float* ar[3]   = {(const float*)d_in[6],  (const float*)d_in[10], (const float*)d_in[14]};
    const float* bias[3] = {(const float*)d_in[7],  (const float*)d_in[11], (const float*)d_in[15]};
    const float* Wg1 = (const float*)d_in[16];
    const float* bg1 = (const float*)d_in[17];
    const float* Wg2 = (const float*)d_in[18];
    const float* bg2 = (const float*)d_in[19];
    const float* Wmu = (const float*)d_in[20];
    const float* bmu = (const float*)d_in[21];
    const float* Wlv = (const float*)d_in[22];
    const float* blv = (const float*)d_in[23];

    // workspace ~227 MB (bf16 big buffers; round-2's ~245 MB fit, so this fits)
    char* ws = (char*)d_ws;
    size_t woff = 0;
    auto carve = [&](size_t bytes) {
        void* p = ws + woff;
        woff = (woff + bytes + 255) & ~(size_t)255;
        return p;
    };
    ushort* hA      = (ushort*)carve((size_t)NNODES * 512 * 2);  // aggregated h (bf16)
    ushort* hB      = (ushort*)carve((size_t)NNODES * 512 * 2);  // Wh (bf16); reused as fp32 hg
    float*  el      = (float*) carve((size_t)NNODES * 4 * 4);
    float*  er      = (float*) carve((size_t)NNODES * 4 * 4);
    float*  aw      = (float*) carve((size_t)NEDGES * 4 * 4);
    int*    deg     = (int*)   carve((size_t)NNODES * 4);
    int*    off     = (int*)   carve((size_t)(NNODES + 1) * 4);
    int*    cursor  = (int*)   carve((size_t)NNODES * 4);
    int*    src_csr = (int*)   carve((size_t)NEDGES * 4);
    int*    bsum    = (int*)   carve((size_t)(NB_SCAN + 1) * 4);
    float*  gate    = (float*) carve((size_t)NNODES * 4);
    float*  exn     = (float*) carve((size_t)NNODES * 4);
    int*    gstart  = (int*)   carve((size_t)(NGRAPH + 1) * 4);
    float*  partial = (float*) carve((size_t)NGRAPH * 4 * FINALD * 4);
    float*  gsum    = (float*) carve((size_t)NGRAPH * 4);
    float*  hg      = (float*)hB;  // 25.6 MB into hB's 102.4 MB; Wh3 dead by then

    // ---- CSR build ----
    zero_int_kernel<<<(NNODES + 255) / 256, 256, 0, stream>>>(deg, NNODES);
    count_kernel<<<(NEDGES + 255) / 256, 256, 0, stream>>>(dst, deg);
    scan_block_kernel<<<NB_SCAN, 1024, 0, stream>>>(deg, off, bsum);
    scan_bsum_kernel<<<1, 128, 0, stream>>>(bsum);
    scan_add_kernel<<<NB_SCAN, 1024, 0, stream>>>(off, bsum);
    copy_int_kernel<<<(NNODES + 255) / 256, 256, 0, stream>>>(off, cursor, NNODES);
    scatter_kernel<<<(NEDGES + 255) / 256, 256, 0, stream>>>(src, dst, cursor, src_csr);
    gstart_kernel<<<1, 128, 0, stream>>>(gid, gstart);

    const int Kdim[3]   = {92, 128, 256};
    const int HDs[3]    = {128, 256, 512};
    const int logHD8[3] = {4, 5, 6};
    const int logD[3]   = {5, 6, 7};

    for (int l = 0; l < 3; l++) {
        int K = Kdim[l], HD = HDs[l], D = HD / NHEAD;
        dim3 ggrid((NNODES + 127) / 128, HD / 128);
        if (l == 0)
            sgemm_tile<float, ushort, 128, false><<<ggrid, 256, 0, stream>>>(
                node_feat, W[l], nullptr, hB, NNODES, K, HD);
        else
            sgemm_tile<ushort, ushort, 128, false><<<ggrid, 256, 0, stream>>>(
                hA, W[l], nullptr, hB, NNODES, K, HD);
        eler_wave<<<NNODES, 256, 0, stream>>>(hB, al[l], ar[l], el, er, D, HD);
        attn_softmax<<<(NNODES * NHEAD + 255) / 256, 256, 0, stream>>>(src_csr, off, el, er, aw);
        int total8 = NNODES * (HD / 8);
        gat_aggregate<<<(total8 + 255) / 256, 256, 0, stream>>>(
            src_csr, off, hB, aw, bias[l], hA, HD, logHD8[l], logD[l], total8);
    }

    // ---- attention pooling + heads ----
    sgemm_tile<ushort, float, 64, true><<<dim3((NNODES + 127) / 128, 1), 256, 0, stream>>>(
        hA, Wg1, bg1, hg, NNODES, FINALD, HIDG);
    gate_dot<<<NNODES / 4, 256, 0, stream>>>(hg, Wg2, bg2, gate);
    graph_softmax_kernel<<<NGRAPH, 256, 0, stream>>>(gate, gstart, exn, gsum);
    pool_partial<<<dim3(NGRAPH, 4), 128, 0, stream>>>(hA, exn, gstart, partial);
    final_kernel<<<NGRAPH, 128, 0, stream>>>(partial, gsum, Wmu, bmu, Wlv, blv, (float*)d_out);
}

// Round 6
// 1056.261 us; speedup vs baseline: 3.8517x; 1.3893x over previous
//
#include <hip/hip_runtime.h>
#include <math.h>

#define NNODES 100000
#define NEDGES 800000
#define NGRAPH 64
#define NHEAD  4
#define FINALD 512
#define HIDG   64
#define LATD   128
#define NB_SCAN 98  // ceil(NNODES/1024)

typedef unsigned int uint;
typedef unsigned short ushort;
typedef __attribute__((ext_vector_type(8))) short bf16x8;
typedef __attribute__((ext_vector_type(4))) float f32x4;

// ---- bf16 helpers (buffers are ushort; fp32<->bf16 by bit ops, RNE pack) ----
__device__ __forceinline__ float bflo(uint u) { return __uint_as_float(u << 16); }
__device__ __forceinline__ float bfhi(uint u) { return __uint_as_float(u & 0xffff0000u); }
__device__ __forceinline__ float bf2f(ushort s) { return __uint_as_float((uint)s << 16); }
__device__ __forceinline__ ushort f2bf(float f) {
    uint u = __float_as_uint(f);
    return (ushort)((u + 0x7fffu + ((u >> 16) & 1u)) >> 16);
}
__device__ __forceinline__ uint pack2(float a, float b) {
    return (uint)f2bf(a) | ((uint)f2bf(b) << 16);
}
__device__ __forceinline__ float ldS(const float* p) { return *p; }
__device__ __forceinline__ float ldS(const ushort* p) { return bf2f(*p); }
__device__ __forceinline__ void loadA4(const float* p, float* v) {
    float4 t = *(const float4*)p;
    v[0] = t.x; v[1] = t.y; v[2] = t.z; v[3] = t.w;
}
__device__ __forceinline__ void storeC4(ushort* p, const float* v) {
    uint2 t;
    t.x = pack2(v[0], v[1]);
    t.y = pack2(v[2], v[3]);
    *(uint2*)p = t;
}

// ======================== CSR build ========================
__global__ void zero_int_kernel(int* p, int n) {
    int i = blockIdx.x * blockDim.x + threadIdx.x;
    if (i < n) p[i] = 0;
}
__global__ void copy_int_kernel(const int* a, int* b, int n) {
    int i = blockIdx.x * blockDim.x + threadIdx.x;
    if (i < n) b[i] = a[i];
}
__global__ void count_kernel(const int* __restrict__ dst, int* __restrict__ deg) {
    int e = blockIdx.x * blockDim.x + threadIdx.x;
    if (e < NEDGES) atomicAdd(&deg[dst[e]], 1);
}
__global__ __launch_bounds__(1024) void scan_block_kernel(const int* __restrict__ deg,
                                                          int* __restrict__ off,
                                                          int* __restrict__ bsum) {
    __shared__ int buf[1024];
    int t = threadIdx.x;
    int i = blockIdx.x * 1024 + t;
    int x = (i < NNODES) ? deg[i] : 0;
    buf[t] = x;
    __syncthreads();
    for (int s = 1; s < 1024; s <<= 1) {
        int v = (t >= s) ? buf[t - s] : 0;
        __syncthreads();
        buf[t] += v;
        __syncthreads();
    }
    if (i < NNODES) off[i] = buf[t] - x;  // exclusive within block
    if (t == 1023) bsum[blockIdx.x] = buf[1023];
}
__global__ __launch_bounds__(128) void scan_bsum_kernel(int* __restrict__ bsum) {
    __shared__ int buf[128];
    int t = threadIdx.x;
    int x = (t < NB_SCAN) ? bsum[t] : 0;
    buf[t] = x;
    __syncthreads();
    for (int s = 1; s < 128; s <<= 1) {
        int v = (t >= s) ? buf[t - s] : 0;
        __syncthreads();
        buf[t] += v;
        __syncthreads();
    }
    if (t < NB_SCAN) bsum[t] = buf[t] - x;
    if (t == 0) bsum[NB_SCAN] = buf[NB_SCAN - 1];
}
__global__ __launch_bounds__(1024) void scan_add_kernel(int* __restrict__ off,
                                                        const int* __restrict__ bsum) {
    int i = blockIdx.x * 1024 + threadIdx.x;
    if (i < NNODES) off[i] += bsum[blockIdx.x];
    if (i == 0) off[NNODES] = bsum[NB_SCAN];
}
__global__ void scatter_kernel(const int* __restrict__ src, const int* __restrict__ dst,
                               int* __restrict__ cursor, int* __restrict__ src_csr) {
    int e = blockIdx.x * blockDim.x + threadIdx.x;
    if (e >= NEDGES) return;
    int p = atomicAdd(&cursor[dst[e]], 1);
    src_csr[p] = src[e];
}
__global__ void gstart_kernel(const int* __restrict__ gid, int* __restrict__ gstart) {
    int g = blockIdx.x * blockDim.x + threadIdx.x;
    if (g > NGRAPH) return;
    int lo = 0, hi = NNODES;
    while (lo < hi) {
        int mid = (lo + hi) >> 1;
        if (gid[mid] < g) lo = mid + 1; else hi = mid;
    }
    gstart[g] = lo;
}

// ---- weight convert+transpose: W[K][N] fp32 -> Bt[N][K] bf16 ----
__global__ void wconv_kernel(const float* __restrict__ W, ushort* __restrict__ Bt,
                             int K, int N) {
    int idx = blockIdx.x * blockDim.x + threadIdx.x;
    if (idx >= K * N) return;
    int k = idx / N, n = idx - k * N;
    Bt[(size_t)n * K + k] = f2bf(W[idx]);
}

// ======================== MFMA bf16 GEMM ========================
// C[M,N] = A[M,K] @ B[K,N]; A bf16 [M][K], Bt bf16 [N][K] (pre-transposed).
// Block: 256 threads = 4 waves (2x2). BN=128: wave does 64x64; BN=64: 64x32.
// K must be a multiple of 32. fp32 accumulate (MFMA AGPRs).
template <int BN, bool RELU, typename TC>
__global__ __launch_bounds__(256) void mfma_gemm(const ushort* __restrict__ A,
                                                 const ushort* __restrict__ Bt,
                                                 const float* __restrict__ bias,
                                                 TC* __restrict__ C,
                                                 int M, int K, int N) {
    constexpr int WNS = BN / 2;   // wave N span
    constexpr int NT = WNS / 16;  // n-tiles per wave
    __shared__ ushort Alds[128][40];  // +8 pad: 80B row stride -> 2-way banks (free)
    __shared__ ushort Blds[BN][40];
    int tid = threadIdx.x;
    int wave = tid >> 6, lane = tid & 63;
    int wm = wave & 1, wn = wave >> 1;
    int quad = lane >> 4, l16 = lane & 15;
    int rowBase = blockIdx.x * 128;
    int colBase = blockIdx.y * BN;

    f32x4 acc[4][NT];
#pragma unroll
    for (int i = 0; i < 4; i++)
#pragma unroll
        for (int j = 0; j < NT; j++) acc[i][j] = (f32x4){0.f, 0.f, 0.f, 0.f};

    for (int k0 = 0; k0 < K; k0 += 32) {
        // stage A: 128 rows x 32 k = 4096 bf16; 256 threads x 2 uint4 (16 bf16)
        {
            int r = tid >> 1;
            int c0 = (tid & 1) * 8;  // chunks c0 and c0+16 -> covers k 0..31
            int row = rowBase + r;
            uint4 v0 = make_uint4(0u, 0u, 0u, 0u);
            uint4 v1 = make_uint4(0u, 0u, 0u, 0u);
            if (row < M) {
                const ushort* ap = &A[(size_t)row * K + k0];
                v0 = *(const uint4*)&ap[c0];
                v1 = *(const uint4*)&ap[c0 + 16];
            }
            *(uint4*)&Alds[r][c0] = v0;
            *(uint4*)&Alds[r][c0 + 16] = v1;
        }
        // stage B (transposed source): BN rows x 32 k
        if constexpr (BN == 128) {
            int r = tid >> 1;
            int c0 = (tid & 1) * 8;
            const ushort* bp = &Bt[(size_t)(colBase + r) * K + k0];
            *(uint4*)&Blds[r][c0] = *(const uint4*)&bp[c0];
            *(uint4*)&Blds[r][c0 + 16] = *(const uint4*)&bp[c0 + 16];
        } else {
            int r = tid >> 2, ch = tid & 3;
            uint4 v = *(const uint4*)&Bt[(size_t)(colBase + r) * K + k0 + ch * 8];
            *(uint4*)&Blds[r][ch * 8] = v;
        }
        __syncthreads();
        bf16x8 af[4], bf[NT];
#pragma unroll
        for (int i = 0; i < 4; i++)
            af[i] = *(const bf16x8*)&Alds[wm * 64 + i * 16 + l16][quad * 8];
#pragma unroll
        for (int j = 0; j < NT; j++)
            bf[j] = *(const bf16x8*)&Blds[wn * WNS + j * 16 + l16][quad * 8];
#pragma unroll
        for (int i = 0; i < 4; i++)
#pragma unroll
            for (int j = 0; j < NT; j++)
                acc[i][j] = __builtin_amdgcn_mfma_f32_16x16x32_bf16(af[i], bf[j], acc[i][j], 0, 0, 0);
        __syncthreads();
    }
    // epilogue: D[row=quad*4+r][col=lane&15] per 16x16 tile
#pragma unroll
    for (int i = 0; i < 4; i++) {
#pragma unroll
        for (int j = 0; j < NT; j++) {
            int col = colBase + wn * WNS + j * 16 + l16;
            float bb = RELU ? bias[col] : 0.f;
#pragma unroll
            for (int r = 0; r < 4; r++) {
                int row = rowBase + wm * 64 + i * 16 + quad * 4 + r;
                if (row < M) {
                    float x = acc[i][j][r];
                    if constexpr (RELU) x = fmaxf(x + bb, 0.f);
                    if constexpr (sizeof(TC) == 2)
                        ((ushort*)C)[(size_t)row * N + col] = f2bf(x);
                    else
                        ((float*)C)[(size_t)row * N + col] = x;
                }
            }
        }
    }
}

// ======================== vector SGEMM (layer 1 only: K=92, A fp32) ========================
template <typename TA, typename TC, int BN, bool RELU>
__global__ __launch_bounds__(256) void sgemm_tile(const TA* __restrict__ A,
                                                  const float* __restrict__ B,
                                                  const float* __restrict__ bias,
                                                  TC* __restrict__ C,
                                                  int M, int K, int N) {
    constexpr int CW = (BN == 128) ? 8 : 4;
    __shared__ float As[16][132];
    __shared__ float Bs[16][BN + 4];
    int tid = threadIdx.x;
    int rowBase = blockIdx.x * 128;
    int colBase = blockIdx.y * BN;
    int tx = tid & 15, ty = tid >> 4;
    float acc[8][CW];
#pragma unroll
    for (int i = 0; i < 8; i++)
#pragma unroll
        for (int j = 0; j < CW; j++) acc[i][j] = 0.f;

    for (int k0 = 0; k0 < K; k0 += 16) {
        bool fullk = (k0 + 16 <= K);
#pragma unroll
        for (int i = 0; i < 2; i++) {
            int r = (tid >> 2) + i * 64;
            int kq = (tid & 3) * 4;
            int row = rowBase + r;
            float v[4] = {0.f, 0.f, 0.f, 0.f};
            if (row < M) {
                if (fullk) {
                    loadA4(&A[(size_t)row * K + k0 + kq], v);
                } else {
#pragma unroll
                    for (int j = 0; j < 4; j++) {
                        int k = k0 + kq + j;
                        if (k < K) v[j] = ldS(&A[(size_t)row * K + k]);
                    }
                }
            }
            As[kq + 0][r] = v[0];
            As[kq + 1][r] = v[1];
            As[kq + 2][r] = v[2];
            As[kq + 3][r] = v[3];
        }
        {
            int kk = tid >> 4;
            int k = k0 + kk;
            constexpr int PER = BN / 16;
            int cq = (tid & 15) * PER;
#pragma unroll
            for (int c = 0; c < PER; c += 4) {
                float4 v = make_float4(0.f, 0.f, 0.f, 0.f);
                if (k < K) v = *(const float4*)&B[(size_t)k * N + colBase + cq + c];
                *(float4*)&Bs[kk][cq + c] = v;
            }
        }
        __syncthreads();
#pragma unroll
        for (int kk = 0; kk < 16; kk++) {
            float a[8], b[CW];
            *(float4*)&a[0] = *(const float4*)&As[kk][ty * 4];
            *(float4*)&a[4] = *(const float4*)&As[kk][64 + ty * 4];
            *(float4*)&b[0] = *(const float4*)&Bs[kk][tx * 4];
            if constexpr (CW == 8) *(float4*)&b[4] = *(const float4*)&Bs[kk][64 + tx * 4];
#pragma unroll
            for (int i = 0; i < 8; i++)
#pragma unroll
                for (int j = 0; j < CW; j++)
                    acc[i][j] = fmaf(a[i], b[j], acc[i][j]);
        }
        __syncthreads();
    }
#pragma unroll
    for (int i = 0; i < 8; i++) {
        int r = rowBase + ((i < 4) ? (ty * 4 + i) : (64 + ty * 4 + i - 4));
        if (r < M) {
#pragma unroll
            for (int half = 0; half < CW / 4; half++) {
                float v[4];
#pragma unroll
                for (int j = 0; j < 4; j++) v[j] = acc[i][half * 4 + j];
                storeC4(&C[(size_t)r * N + colBase + half * 64 + tx * 4], v);
            }
        }
    }
}

// ======================== el/er: one wave per (node, head); Wh bf16 ========================
__global__ __launch_bounds__(256) void eler_wave(const ushort* __restrict__ Wh,
                                                 const float* __restrict__ al,
                                                 const float* __restrict__ ar,
                                                 float* __restrict__ el,
                                                 float* __restrict__ er,
                                                 int D, int HD) {
    int n = blockIdx.x;
    int h = threadIdx.x >> 6;
    int lane = threadIdx.x & 63;
    const ushort* w = Wh + (size_t)n * HD + h * D;
    const float* pa = al + h * D;
    const float* pb = ar + h * D;
    float sl = 0.f, sr = 0.f;
    if (lane < D) {
        float v = bf2f(w[lane]);
        sl = v * pa[lane];
        sr = v * pb[lane];
    }
    if (D == 128) {
        float v = bf2f(w[lane + 64]);
        sl = fmaf(v, pa[lane + 64], sl);
        sr = fmaf(v, pb[lane + 64], sr);
    }
#pragma unroll
    for (int o = 32; o > 0; o >>= 1) {
        sl += __shfl_down(sl, o, 64);
        sr += __shfl_down(sr, o, 64);
    }
    if (lane == 0) {
        el[n * 4 + h] = sl;
        er[n * 4 + h] = sr;
    }
}

// ======================== edge softmax over CSR in-edges ========================
__global__ void attn_softmax(const int* __restrict__ src_csr, const int* __restrict__ off,
                             const float* __restrict__ el, const float* __restrict__ er,
                             float* __restrict__ aw) {
    int idx = blockIdx.x * blockDim.x + threadIdx.x;
    if (idx >= NNODES * NHEAD) return;
    int n = idx >> 2, h = idx & 3;
    int i0 = off[n], i1 = off[n + 1];
    if (i0 == i1) return;
    float ern = er[n * 4 + h];
    float m = -1e30f;
    for (int i = i0; i < i1; i += 8) {
        int cnt = i1 - i; if (cnt > 8) cnt = 8;
        int s8[8];
#pragma unroll
        for (int j = 0; j < 8; j++)
            if (j < cnt) s8[j] = src_csr[i + j];
#pragma unroll
        for (int j = 0; j < 8; j++) {
            if (j < cnt) {
                float x = el[s8[j] * 4 + h] + ern;
                x = (x >= 0.f) ? x : 0.2f * x;
                aw[(i + j) * 4 + h] = x;
                m = fmaxf(m, x);
            }
        }
    }
    float s = 0.f;
    for (int i = i0; i < i1; i++) {
        float v = expf(aw[i * 4 + h] - m);
        aw[i * 4 + h] = v;
        s += v;
    }
    float inv = 1.f / fmaxf(s, 1e-9f);
    for (int i = i0; i < i1; i++) aw[i * 4 + h] *= inv;
}

// ======================== aggregate: 8 bf16 dims/thread, batched prefetch ========================
__global__ __launch_bounds__(256) void gat_aggregate(const int* __restrict__ src_csr,
                                                     const int* __restrict__ off,
                                                     const ushort* __restrict__ Wh,
                                                     const float* __restrict__ aw,
                                                     const float* __restrict__ bias,
                                                     ushort* __restrict__ out,
                                                     int HD, int logHD8, int logD, int total8) {
    int idx = blockIdx.x * blockDim.x + threadIdx.x;
    if (idx >= total8) return;
    int n = idx >> logHD8;
    int d = (idx & ((1 << logHD8) - 1)) << 3;  // 8 dims per thread
    int h = d >> logD;
    int i0 = off[n], i1 = off[n + 1];
    float acc[8] = {0.f, 0.f, 0.f, 0.f, 0.f, 0.f, 0.f, 0.f};
    for (int i = i0; i < i1; i += 8) {
        int cnt = i1 - i; if (cnt > 8) cnt = 8;
        int s8[8]; float w8[8];
#pragma unroll
        for (int j = 0; j < 8; j++) {
            if (j < cnt) {
                s8[j] = src_csr[i + j];
                w8[j] = aw[(i + j) * 4 + h];
            }
        }
#pragma unroll
        for (int j = 0; j < 8; j++) {
            if (j < cnt) {
                uint4 v = *(const uint4*)&Wh[(size_t)s8[j] * HD + d];
                float w = w8[j];
                acc[0] = fmaf(w, bflo(v.x), acc[0]);
                acc[1] = fmaf(w, bfhi(v.x), acc[1]);
                acc[2] = fmaf(w, bflo(v.y), acc[2]);
                acc[3] = fmaf(w, bfhi(v.y), acc[3]);
                acc[4] = fmaf(w, bflo(v.z), acc[4]);
                acc[5] = fmaf(w, bfhi(v.z), acc[5]);
                acc[6] = fmaf(w, bflo(v.w), acc[6]);
                acc[7] = fmaf(w, bfhi(v.w), acc[7]);
            }
        }
    }
    uint4 o;
    float r[8];
#pragma unroll
    for (int j = 0; j < 8; j++) {
        float x = acc[j] + bias[d + j];
        r[j] = (x > 0.f) ? x : (expf(x) - 1.f);
    }
    o.x = pack2(r[0], r[1]);
    o.y = pack2(r[2], r[3]);
    o.z = pack2(r[4], r[5]);
    o.w = pack2(r[6], r[7]);
    *(uint4*)&out[(size_t)n * HD + d] = o;
}

// ======================== gate: hg @ Wg2 + bg2 (one wave per node) ========================
__global__ __launch_bounds__(256) void gate_dot(const float* __restrict__ hg,
                                                const float* __restrict__ Wg2,
                                                const float* __restrict__ bg2,
                                                float* __restrict__ gate) {
    int n = blockIdx.x * 4 + (threadIdx.x >> 6);
    int lane = threadIdx.x & 63;
    float v = hg[(size_t)n * HIDG + lane] * Wg2[lane];
#pragma unroll
    for (int o = 32; o > 0; o >>= 1)
        v += __shfl_down(v, o, 64);
    if (lane == 0) gate[n] = v + bg2[0];
}

// ======================== per-graph softmax over node gates ========================
__global__ __launch_bounds__(256) void graph_softmax_kernel(const float* __restrict__ gate,
                                                            const int* __restrict__ gstart,
                                                            float* __restrict__ exn,
                                                            float* __restrict__ gsum) {
    int g = blockIdx.x, t = threadIdx.x;
    int n0 = gstart[g], n1 = gstart[g + 1];
    __shared__ float red[256];
    float m = -1e30f;
    for (int n = n0 + t; n < n1; n += 256) m = fmaxf(m, gate[n]);
    red[t] = m; __syncthreads();
    for (int s = 128; s > 0; s >>= 1) {
        if (t < s) red[t] = fmaxf(red[t], red[t + s]);
        __syncthreads();
    }
    m = red[0]; __syncthreads();
    float sum = 0.f;
    for (int n = n0 + t; n < n1; n += 256) {
        float v = expf(gate[n] - m);
        exn[n] = v;
        sum += v;
    }
    red[t] = sum; __syncthreads();
    for (int s = 128; s > 0; s >>= 1) {
        if (t < s) red[t] += red[t + s];
        __syncthreads();
    }
    if (t == 0) gsum[g] = red[0];
}

// ======================== pooled partial sums (4 blocks per graph); h bf16 ========================
__global__ __launch_bounds__(128) void pool_partial(const ushort* __restrict__ h,
                                                    const float* __restrict__ exn,
                                                    const int* __restrict__ gstart,
                                                    float* __restrict__ partial) {
    int g = blockIdx.x, q = blockIdx.y;
    int n0 = gstart[g], n1 = gstart[g + 1];
    int len = n1 - n0;
    int chunk = (len + 3) >> 2;
    int s = n0 + q * chunk;
    int e = s + chunk; if (e > n1) e = n1;
    int d4 = threadIdx.x;
    const uint2* h2 = (const uint2*)h;
    float a0 = 0.f, a1 = 0.f, a2 = 0.f, a3 = 0.f;
    for (int n = s; n < e; n++) {
        float w = exn[n];
        uint2 v = h2[(size_t)n * 128 + d4];
        a0 = fmaf(w, bflo(v.x), a0);
        a1 = fmaf(w, bfhi(v.x), a1);
        a2 = fmaf(w, bflo(v.y), a2);
        a3 = fmaf(w, bfhi(v.y), a3);
    }
    *(float4*)&partial[((size_t)(g * 4 + q)) * FINALD + d4 * 4] = make_float4(a0, a1, a2, a3);
}

// ======================== final heads ========================
__global__ __launch_bounds__(128) void final_kernel(const float* __restrict__ partial,
                                                    const float* __restrict__ gsum,
                                                    const float* __restrict__ Wmu,
                                                    const float* __restrict__ bmu,
                                                    const float* __restrict__ Wlv,
                                                    const float* __restrict__ blv,
                                                    float* __restrict__ out) {
    int g = blockIdx.x, j = threadIdx.x;
    const float* p = partial + (size_t)g * 4 * FINALD;
    float am = 0.f, av = 0.f;
    for (int k = 0; k < FINALD; k++) {
        float pv = p[k] + p[FINALD + k] + p[2 * FINALD + k] + p[3 * FINALD + k];
        am = fmaf(pv, Wmu[k * LATD + j], am);
        av = fmaf(pv, Wlv[k * LATD + j], av);
    }
    float inv = 1.f / fmaxf(gsum[g], 1e-9f);
    out[g * LATD + j] = am * inv + bmu[j];
    out[NGRAPH * LATD + g * LATD + j] = av * inv + blv[j];
}

// ======================== driver ========================
extern "C" void kernel_launch(void* const* d_in, const int* in_sizes, int n_in,
                              void* d_out, int out_size, void* d_ws, size_t ws_size,
                              hipStream_t stream) {
    (void)in_sizes; (void)n_in; (void)out_size; (void)ws_size;
    const float* node_feat = (const float*)d_in[0];
    const int* src = (const int*)d_in[1];
    const int* dst = (const int*)d_in[2];
    const int* gid = (const int*)d_in[3];
    const float* W[3]    = {(const float*)d_in[4],  (const float*)d_in[8],  (const float*)d_in[12]};
    const float* al[3]   = {(const float*)d_in[5],  (const float*)d_in[9],  (const float*)d_in[13]};
    const float* ar[3]   = {(const float*)d_in[6],  (const float*)d_in[10], (const float*)d_in[14]};
    const float* bias[3] = {(const float*)d_in[7],  (const float*)d_in[11], (const float*)d_in[15]};
    const float* Wg1 = (const float*)d_in[16];
    const float* bg1 = (const float*)d_in[17];
    const float* Wg2 = (const float*)d_in[18];
    const float* bg2 = (const float*)d_in[19];
    const float* Wmu = (const float*)d_in[20];
    const float* bmu = (const float*)d_in[21];
    const float* Wlv = (const float*)d_in[22];
    const float* blv = (const float*)d_in[23];

    // workspace ~228 MB (bf16 big buffers; fits the ~256 MB workspace)
    char* ws = (char*)d_ws;
    size_t woff = 0;
    auto carve = [&](size_t bytes) {
        void* p = ws + woff;
        woff = (woff + bytes + 255) & ~(size_t)255;
        return p;
    };
    ushort* hA      = (ushort*)carve((size_t)NNODES * 512 * 2);  // aggregated h (bf16)
    ushort* hB      = (ushort*)carve((size_t)NNODES * 512 * 2);  // Wh (bf16); reused as fp32 hg
    float*  el      = (float*) carve((size_t)NNODES * 4 * 4);
    float*  er      = (float*) carve((size_t)NNODES * 4 * 4);
    float*  aw      = (float*) carve((size_t)NEDGES * 4 * 4);
    int*    deg     = (int*)   carve((size_t)NNODES * 4);
    int*    off     = (int*)   carve((size_t)(NNODES + 1) * 4);
    int*    cursor  = (int*)   carve((size_t)NNODES * 4);
    int*    src_csr = (int*)   carve((size_t)NEDGES * 4);
    int*    bsum    = (int*)   carve((size_t)(NB_SCAN + 1) * 4);
    float*  gate    = (float*) carve((size_t)NNODES * 4);
    float*  exn     = (float*) carve((size_t)NNODES * 4);
    int*    gstart  = (int*)   carve((size_t)(NGRAPH + 1) * 4);
    float*  partial = (float*) carve((size_t)NGRAPH * 4 * FINALD * 4);
    float*  gsum    = (float*) carve((size_t)NGRAPH * 4);
    ushort* Bt2     = (ushort*)carve((size_t)128 * 256 * 2);  // W2^T bf16 [256][128]
    ushort* Bt3     = (ushort*)carve((size_t)256 * 512 * 2);  // W3^T bf16 [512][256]
    ushort* Btg     = (ushort*)carve((size_t)512 * 64 * 2);   // Wg1^T bf16 [64][512]
    float*  hg      = (float*)hB;  // 25.6 MB into hB's 102.4 MB; Wh3 dead by then

    // ---- CSR build + weight conversion ----
    zero_int_kernel<<<(NNODES + 255) / 256, 256, 0, stream>>>(deg, NNODES);
    count_kernel<<<(NEDGES + 255) / 256, 256, 0, stream>>>(dst, deg);
    scan_block_kernel<<<NB_SCAN, 1024, 0, stream>>>(deg, off, bsum);
    scan_bsum_kernel<<<1, 128, 0, stream>>>(bsum);
    scan_add_kernel<<<NB_SCAN, 1024, 0, stream>>>(off, bsum);
    copy_int_kernel<<<(NNODES + 255) / 256, 256, 0, stream>>>(off, cursor, NNODES);
    scatter_kernel<<<(NEDGES + 255) / 256, 256, 0, stream>>>(src, dst, cursor, src_csr);
    gstart_kernel<<<1, 128, 0, stream>>>(gid, gstart);
    wconv_kernel<<<(128 * 256 + 255) / 256, 256, 0, stream>>>(W[1], Bt2, 128, 256);
    wconv_kernel<<<(256 * 512 + 255) / 256, 256, 0, stream>>>(W[2], Bt3, 256, 512);
    wconv_kernel<<<(512 * 64 + 255) / 256, 256, 0, stream>>>(Wg1, Btg, 512, 64);

    const int Kdim[3]   = {92, 128, 256};
    const int HDs[3]    = {128, 256, 512};
    const int logHD8[3] = {4, 5, 6};
    const int logD[3]   = {5, 6, 7};
    const int MB = (NNODES + 127) / 128;  // 782

    for (int l = 0; l < 3; l++) {
        int K = Kdim[l], HD = HDs[l], D = HD / NHEAD;
        if (l == 0) {
            sgemm_tile<float, ushort, 128, false><<<dim3(MB, HD / 128), 256, 0, stream>>>(
                node_feat, W[0], nullptr, hB, NNODES, K, HD);
        } else if (l == 1) {
            mfma_gemm<128, false, ushort><<<dim3(MB, HD / 128), 256, 0, stream>>>(
                hA, Bt2, nullptr, hB, NNODES, K, HD);
        } else {
            mfma_gemm<128, false, ushort><<<dim3(MB, HD / 128), 256, 0, stream>>>(
                hA, Bt3, nullptr, hB, NNODES, K, HD);
        }
        eler_wave<<<NNODES, 256, 0, stream>>>(hB, al[l], ar[l], el, er, D, HD);
        attn_softmax<<<(NNODES * NHEAD + 255) / 256, 256, 0, stream>>>(src_csr, off, el, er, aw);
        int total8 = NNODES * (HD / 8);
        gat_aggregate<<<(total8 + 255) / 256, 256, 0, stream>>>(
            src_csr, off, hB, aw, bias[l], hA, HD, logHD8[l], logD[l], total8);
    }

    // ---- attention pooling + heads ----
    mfma_gemm<64, true, float><<<dim3(MB, 1), 256, 0, stream>>>(
        hA, Btg, bg1, hg, NNODES, FINALD, HIDG);
    gate_dot<<<NNODES / 4, 256, 0, stream>>>(hg, Wg2, bg2, gate);
    graph_softmax_kernel<<<NGRAPH, 256, 0, stream>>>(gate, gstart, exn, gsum);
    pool_partial<<<dim3(NGRAPH, 4), 128, 0, stream>>>(hA, exn, gstart, partial);
    final_kernel<<<NGRAPH, 128, 0, stream>>>(partial, gsum, Wmu, bmu, Wlv, blv, (float*)d_out);
}

// Round 7
// 936.754 us; speedup vs baseline: 4.3431x; 1.1276x over previous
//
#include <hip/hip_runtime.h>
#include <math.h>

#define NNODES 100000
#define NEDGES 800000
#define NGRAPH 64
#define NHEAD  4
#define FINALD 512
#define HIDG   64
#define LATD   128
#define K1P    96   // layer-1 K padded (92 -> 96)
#define NB_SCAN 98  // ceil(NNODES/1024)

typedef unsigned int uint;
typedef unsigned short ushort;
typedef __attribute__((ext_vector_type(8))) short bf16x8;
typedef __attribute__((ext_vector_type(4))) float f32x4;

// ---- bf16 helpers ----
__device__ __forceinline__ float bflo(uint u) { return __uint_as_float(u << 16); }
__device__ __forceinline__ float bfhi(uint u) { return __uint_as_float(u & 0xffff0000u); }
__device__ __forceinline__ ushort f2bf(float f) {
    uint u = __float_as_uint(f);
    return (ushort)((u + 0x7fffu + ((u >> 16) & 1u)) >> 16);
}
__device__ __forceinline__ uint pack2(float a, float b) {
    return (uint)f2bf(a) | ((uint)f2bf(b) << 16);
}

// ======================== CSR build ========================
__global__ void zero_int_kernel(int* p, int n) {
    int i = blockIdx.x * blockDim.x + threadIdx.x;
    if (i < n) p[i] = 0;
}
__global__ void copy_int_kernel(const int* a, int* b, int n) {
    int i = blockIdx.x * blockDim.x + threadIdx.x;
    if (i < n) b[i] = a[i];
}
__global__ void count_kernel(const int* __restrict__ dst, int* __restrict__ deg) {
    int e = blockIdx.x * blockDim.x + threadIdx.x;
    if (e < NEDGES) atomicAdd(&deg[dst[e]], 1);
}
__global__ __launch_bounds__(1024) void scan_block_kernel(const int* __restrict__ deg,
                                                          int* __restrict__ off,
                                                          int* __restrict__ bsum) {
    __shared__ int buf[1024];
    int t = threadIdx.x;
    int i = blockIdx.x * 1024 + t;
    int x = (i < NNODES) ? deg[i] : 0;
    buf[t] = x;
    __syncthreads();
    for (int s = 1; s < 1024; s <<= 1) {
        int v = (t >= s) ? buf[t - s] : 0;
        __syncthreads();
        buf[t] += v;
        __syncthreads();
    }
    if (i < NNODES) off[i] = buf[t] - x;
    if (t == 1023) bsum[blockIdx.x] = buf[1023];
}
__global__ __launch_bounds__(128) void scan_bsum_kernel(int* __restrict__ bsum) {
    __shared__ int buf[128];
    int t = threadIdx.x;
    int x = (t < NB_SCAN) ? bsum[t] : 0;
    buf[t] = x;
    __syncthreads();
    for (int s = 1; s < 128; s <<= 1) {
        int v = (t >= s) ? buf[t - s] : 0;
        __syncthreads();
        buf[t] += v;
        __syncthreads();
    }
    if (t < NB_SCAN) bsum[t] = buf[t] - x;
    if (t == 0) bsum[NB_SCAN] = buf[NB_SCAN - 1];
}
__global__ __launch_bounds__(1024) void scan_add_kernel(int* __restrict__ off,
                                                        const int* __restrict__ bsum) {
    int i = blockIdx.x * 1024 + threadIdx.x;
    if (i < NNODES) off[i] += bsum[blockIdx.x];
    if (i == 0) off[NNODES] = bsum[NB_SCAN];
}
__global__ void scatter_kernel(const int* __restrict__ src, const int* __restrict__ dst,
                               int* __restrict__ cursor, int* __restrict__ src_csr) {
    int e = blockIdx.x * blockDim.x + threadIdx.x;
    if (e >= NEDGES) return;
    int p = atomicAdd(&cursor[dst[e]], 1);
    src_csr[p] = src[e];
}
__global__ void gstart_kernel(const int* __restrict__ gid, int* __restrict__ gstart) {
    int g = blockIdx.x * blockDim.x + threadIdx.x;
    if (g > NGRAPH) return;
    int lo = 0, hi = NNODES;
    while (lo < hi) {
        int mid = (lo + hi) >> 1;
        if (gid[mid] < g) lo = mid + 1; else hi = mid;
    }
    gstart[g] = lo;
}

// ---- weight convert+transpose with K padding: W[K][N] fp32 -> Bt[N][KP] bf16 ----
__global__ void wconv_pad_kernel(const float* __restrict__ W, ushort* __restrict__ Bt,
                                 int K, int KP, int N) {
    int idx = blockIdx.x * blockDim.x + threadIdx.x;
    if (idx >= N * KP) return;
    int n = idx / KP, k = idx - n * KP;
    Bt[idx] = (k < K) ? f2bf(W[(size_t)k * N + n]) : (ushort)0;
}

// ---- node_feat fp32 [N][92] -> x0 bf16 [N][96] (zero-padded) ----
__global__ void conv_x0_kernel(const float* __restrict__ nf, ushort* __restrict__ x0) {
    int idx = blockIdx.x * blockDim.x + threadIdx.x;
    if (idx >= NNODES * K1P) return;
    int n = idx / K1P, k = idx - n * K1P;
    x0[idx] = (k < 92) ? f2bf(nf[(size_t)n * 92 + k]) : (ushort)0;
}

// ======================== MFMA bf16 GEMM ========================
// C[M,N] = A[M,K] @ B; A bf16 [M][K], Bt bf16 [N][K] (pre-transposed).
// 256 threads = 4 waves (2x2). BN=128: wave 64x64; BN=64: wave 64x32. K % 32 == 0.
template <int BN, bool RELU, typename TC>
__global__ __launch_bounds__(256) void mfma_gemm(const ushort* __restrict__ A,
                                                 const ushort* __restrict__ Bt,
                                                 const float* __restrict__ bias,
                                                 TC* __restrict__ C,
                                                 int M, int K, int N) {
    constexpr int WNS = BN / 2;
    constexpr int NT = WNS / 16;
    __shared__ ushort Alds[128][40];
    __shared__ ushort Blds[BN][40];
    int tid = threadIdx.x;
    int wave = tid >> 6, lane = tid & 63;
    int wm = wave & 1, wn = wave >> 1;
    int quad = lane >> 4, l16 = lane & 15;
    int rowBase = blockIdx.x * 128;
    int colBase = blockIdx.y * BN;

    f32x4 acc[4][NT];
#pragma unroll
    for (int i = 0; i < 4; i++)
#pragma unroll
        for (int j = 0; j < NT; j++) acc[i][j] = (f32x4){0.f, 0.f, 0.f, 0.f};

    for (int k0 = 0; k0 < K; k0 += 32) {
        {
            int r = tid >> 1;
            int c0 = (tid & 1) * 8;
            int row = rowBase + r;
            uint4 v0 = make_uint4(0u, 0u, 0u, 0u);
            uint4 v1 = make_uint4(0u, 0u, 0u, 0u);
            if (row < M) {
                const ushort* ap = &A[(size_t)row * K + k0];
                v0 = *(const uint4*)&ap[c0];
                v1 = *(const uint4*)&ap[c0 + 16];
            }
            *(uint4*)&Alds[r][c0] = v0;
            *(uint4*)&Alds[r][c0 + 16] = v1;
        }
        if constexpr (BN == 128) {
            int r = tid >> 1;
            int c0 = (tid & 1) * 8;
            const ushort* bp = &Bt[(size_t)(colBase + r) * K + k0];
            *(uint4*)&Blds[r][c0] = *(const uint4*)&bp[c0];
            *(uint4*)&Blds[r][c0 + 16] = *(const uint4*)&bp[c0 + 16];
        } else {
            int r = tid >> 2, ch = tid & 3;
            uint4 v = *(const uint4*)&Bt[(size_t)(colBase + r) * K + k0 + ch * 8];
            *(uint4*)&Blds[r][ch * 8] = v;
        }
        __syncthreads();
        bf16x8 af[4], bf[NT];
#pragma unroll
        for (int i = 0; i < 4; i++)
            af[i] = *(const bf16x8*)&Alds[wm * 64 + i * 16 + l16][quad * 8];
#pragma unroll
        for (int j = 0; j < NT; j++)
            bf[j] = *(const bf16x8*)&Blds[wn * WNS + j * 16 + l16][quad * 8];
#pragma unroll
        for (int i = 0; i < 4; i++)
#pragma unroll
            for (int j = 0; j < NT; j++)
                acc[i][j] = __builtin_amdgcn_mfma_f32_16x16x32_bf16(af[i], bf[j], acc[i][j], 0, 0, 0);
        __syncthreads();
    }
#pragma unroll
    for (int i = 0; i < 4; i++) {
#pragma unroll
        for (int j = 0; j < NT; j++) {
            int col = colBase + wn * WNS + j * 16 + l16;
            float bb = RELU ? bias[col] : 0.f;
#pragma unroll
            for (int r = 0; r < 4; r++) {
                int row = rowBase + wm * 64 + i * 16 + quad * 4 + r;
                if (row < M) {
                    float x = acc[i][j][r];
                    if constexpr (RELU) x = fmaxf(x + bb, 0.f);
                    if constexpr (sizeof(TC) == 2)
                        ((ushort*)C)[(size_t)row * N + col] = f2bf(x);
                    else
                        ((float*)C)[(size_t)row * N + col] = x;
                }
            }
        }
    }
}

// ======================== el/er: wave per node, vectorized ========================
// al/ar are [H][D] flattened = HD floats; global dim index == flat index.
template <int HD>
__global__ __launch_bounds__(256) void eler_node(const ushort* __restrict__ Wh,
                                                 const float* __restrict__ al,
                                                 const float* __restrict__ ar,
                                                 float* __restrict__ el,
                                                 float* __restrict__ er) {
    constexpr int D = HD / NHEAD;
    constexpr int LPN = HD / 8;  // lanes carrying data
    constexpr int S = D / 8;     // lanes per head
    int n = blockIdx.x * 4 + (threadIdx.x >> 6);
    int lane = threadIdx.x & 63;
    float sl = 0.f, sr = 0.f;
    if (lane < LPN) {
        int d0 = lane * 8;
        uint4 v = *(const uint4*)&Wh[(size_t)n * HD + d0];
        float w0 = bflo(v.x), w1 = bfhi(v.x), w2 = bflo(v.y), w3 = bfhi(v.y);
        float w4 = bflo(v.z), w5 = bfhi(v.z), w6 = bflo(v.w), w7 = bfhi(v.w);
        float4 a0 = *(const float4*)&al[d0];
        float4 a1 = *(const float4*)&al[d0 + 4];
        float4 b0 = *(const float4*)&ar[d0];
        float4 b1 = *(const float4*)&ar[d0 + 4];
        sl = w0 * a0.x; sl = fmaf(w1, a0.y, sl); sl = fmaf(w2, a0.z, sl); sl = fmaf(w3, a0.w, sl);
        sl = fmaf(w4, a1.x, sl); sl = fmaf(w5, a1.y, sl); sl = fmaf(w6, a1.z, sl); sl = fmaf(w7, a1.w, sl);
        sr = w0 * b0.x; sr = fmaf(w1, b0.y, sr); sr = fmaf(w2, b0.z, sr); sr = fmaf(w3, b0.w, sr);
        sr = fmaf(w4, b1.x, sr); sr = fmaf(w5, b1.y, sr); sr = fmaf(w6, b1.z, sr); sr = fmaf(w7, b1.w, sr);
    }
#pragma unroll
    for (int o = S / 2; o > 0; o >>= 1) {
        sl += __shfl_down(sl, o, 64);
        sr += __shfl_down(sr, o, 64);
    }
    if (lane < LPN && (lane % S) == 0) {
        int h = lane / S;
        el[n * 4 + h] = sl;
        er[n * 4 + h] = sr;
    }
}

// ======================== per-node edge softmax (unnormalized; sum out) ========================
__global__ void attn_node(const int* __restrict__ src_csr, const int* __restrict__ off,
                          const float4* __restrict__ el4, const float4* __restrict__ er4,
                          float4* __restrict__ aw4, float4* __restrict__ nsum4) {
    int n = blockIdx.x * blockDim.x + threadIdx.x;
    if (n >= NNODES) return;
    int i0 = off[n], i1 = off[n + 1];
    float4 ern = er4[n];
    float m0 = -1e30f, m1 = -1e30f, m2 = -1e30f, m3 = -1e30f;
    for (int i = i0; i < i1; i += 8) {
        int cnt = i1 - i; if (cnt > 8) cnt = 8;
        int s8[8];
#pragma unroll
        for (int j = 0; j < 8; j++)
            if (j < cnt) s8[j] = src_csr[i + j];
        float4 e8[8];
#pragma unroll
        for (int j = 0; j < 8; j++)
            if (j < cnt) e8[j] = el4[s8[j]];
#pragma unroll
        for (int j = 0; j < 8; j++) {
            if (j < cnt) {
                float4 x = e8[j];
                x.x += ern.x; x.y += ern.y; x.z += ern.z; x.w += ern.w;
                x.x = (x.x >= 0.f) ? x.x : 0.2f * x.x;
                x.y = (x.y >= 0.f) ? x.y : 0.2f * x.y;
                x.z = (x.z >= 0.f) ? x.z : 0.2f * x.z;
                x.w = (x.w >= 0.f) ? x.w : 0.2f * x.w;
                aw4[i + j] = x;
                m0 = fmaxf(m0, x.x); m1 = fmaxf(m1, x.y);
                m2 = fmaxf(m2, x.z); m3 = fmaxf(m3, x.w);
            }
        }
    }
    float4 s = make_float4(0.f, 0.f, 0.f, 0.f);
    for (int i = i0; i < i1; i++) {
        float4 x = aw4[i];
        x.x = expf(x.x - m0); x.y = expf(x.y - m1);
        x.z = expf(x.z - m2); x.w = expf(x.w - m3);
        s.x += x.x; s.y += x.y; s.z += x.z; s.w += x.w;
        aw4[i] = x;
    }
    nsum4[n] = s;
}

// ======================== aggregate: 16 bf16 dims/thread, 8-edge batch ========================
__global__ __launch_bounds__(256) void gat_aggregate16(const int* __restrict__ src_csr,
                                                       const int* __restrict__ off,
                                                       const ushort* __restrict__ Wh,
                                                       const float* __restrict__ aw,
                                                       const float* __restrict__ nsum,
                                                       const float* __restrict__ bias,
                                                       ushort* __restrict__ out,
                                                       int HD, int logHD16, int logD, int total16) {
    int idx = blockIdx.x * blockDim.x + threadIdx.x;
    if (idx >= total16) return;
    int n = idx >> logHD16;
    int d = (idx & ((1 << logHD16) - 1)) << 4;  // 16 dims per thread
    int h = d >> logD;
    int i0 = off[n], i1 = off[n + 1];
    float acc[16];
#pragma unroll
    for (int j = 0; j < 16; j++) acc[j] = 0.f;
    for (int i = i0; i < i1; i += 8) {
        int cnt = i1 - i; if (cnt > 8) cnt = 8;
        int s8[8]; float w8[8];
#pragma unroll
        for (int j = 0; j < 8; j++) {
            if (j < cnt) {
                s8[j] = src_csr[i + j];
                w8[j] = aw[(i + j) * 4 + h];
            }
        }
        uint4 v0[8], v1[8];
#pragma unroll
        for (int j = 0; j < 8; j++) {
            if (j < cnt) {
                const ushort* p = &Wh[(size_t)s8[j] * HD + d];
                v0[j] = *(const uint4*)p;
                v1[j] = *(const uint4*)(p + 8);
            }
        }
#pragma unroll
        for (int j = 0; j < 8; j++) {
            if (j < cnt) {
                float w = w8[j];
                acc[0]  = fmaf(w, bflo(v0[j].x), acc[0]);
                acc[1]  = fmaf(w, bfhi(v0[j].x), acc[1]);
                acc[2]  = fmaf(w, bflo(v0[j].y), acc[2]);
                acc[3]  = fmaf(w, bfhi(v0[j].y), acc[3]);
                acc[4]  = fmaf(w, bflo(v0[j].z), acc[4]);
                acc[5]  = fmaf(w, bfhi(v0[j].z), acc[5]);
                acc[6]  = fmaf(w, bflo(v0[j].w), acc[6]);
                acc[7]  = fmaf(w, bfhi(v0[j].w), acc[7]);
                acc[8]  = fmaf(w, bflo(v1[j].x), acc[8]);
                acc[9]  = fmaf(w, bfhi(v1[j].x), acc[9]);
                acc[10] = fmaf(w, bflo(v1[j].y), acc[10]);
                acc[11] = fmaf(w, bfhi(v1[j].y), acc[11]);
                acc[12] = fmaf(w, bflo(v1[j].z), acc[12]);
                acc[13] = fmaf(w, bfhi(v1[j].z), acc[13]);
                acc[14] = fmaf(w, bflo(v1[j].w), acc[14]);
                acc[15] = fmaf(w, bfhi(v1[j].w), acc[15]);
            }
        }
    }
    float inv = 1.f / fmaxf(nsum[n * 4 + h], 1e-9f);
    float r[16];
#pragma unroll
    for (int j = 0; j < 16; j++) {
        float x = fmaf(acc[j], inv, 0.f) + bias[d + j];
        r[j] = (x > 0.f) ? x : (expf(x) - 1.f);
    }
    uint4 o0, o1;
    o0.x = pack2(r[0], r[1]);  o0.y = pack2(r[2], r[3]);
    o0.z = pack2(r[4], r[5]);  o0.w = pack2(r[6], r[7]);
    o1.x = pack2(r[8], r[9]);  o1.y = pack2(r[10], r[11]);
    o1.z = pack2(r[12], r[13]); o1.w = pack2(r[14], r[15]);
    ushort* po = &out[(size_t)n * HD + d];
    *(uint4*)po = o0;
    *(uint4*)(po + 8) = o1;
}

// ======================== gate: hg @ Wg2 + bg2 ========================
__global__ __launch_bounds__(256) void gate_dot(const float* __restrict__ hg,
                                                const float* __restrict__ Wg2,
                                                const float* __restrict__ bg2,
                                                float* __restrict__ gate) {
    int n = blockIdx.x * 4 + (threadIdx.x >> 6);
    int lane = threadIdx.x & 63;
    float v = hg[(size_t)n * HIDG + lane] * Wg2[lane];
#pragma unroll
    for (int o = 32; o > 0; o >>= 1)
        v += __shfl_down(v, o, 64);
    if (lane == 0) gate[n] = v + bg2[0];
}

// ======================== per-graph softmax over node gates ========================
__global__ __launch_bounds__(256) void graph_softmax_kernel(const float* __restrict__ gate,
                                                            const int* __restrict__ gstart,
                                                            float* __restrict__ exn,
                                                            float* __restrict__ gsum) {
    int g = blockIdx.x, t = threadIdx.x;
    int n0 = gstart[g], n1 = gstart[g + 1];
    __shared__ float red[256];
    float m = -1e30f;
    for (int n = n0 + t; n < n1; n += 256) m = fmaxf(m, gate[n]);
    red[t] = m; __syncthreads();
    for (int s = 128; s > 0; s >>= 1) {
        if (t < s) red[t] = fmaxf(red[t], red[t + s]);
        __syncthreads();
    }
    m = red[0]; __syncthreads();
    float sum = 0.f;
    for (int n = n0 + t; n < n1; n += 256) {
        float v = expf(gate[n] - m);
        exn[n] = v;
        sum += v;
    }
    red[t] = sum; __syncthreads();
    for (int s = 128; s > 0; s >>= 1) {
        if (t < s) red[t] += red[t + s];
        __syncthreads();
    }
    if (t == 0) gsum[g] = red[0];
}

// ======================== pooled partial sums (4 blocks per graph) ========================
__global__ __launch_bounds__(128) void pool_partial(const ushort* __restrict__ h,
                                                    const float* __restrict__ exn,
                                                    const int* __restrict__ gstart,
                                                    float* __restrict__ partial) {
    int g = blockIdx.x, q = blockIdx.y;
    int n0 = gstart[g], n1 = gstart[g + 1];
    int len = n1 - n0;
    int chunk = (len + 3) >> 2;
    int s = n0 + q * chunk;
    int e = s + chunk; if (e > n1) e = n1;
    int d4 = threadIdx.x;
    const uint2* h2 = (const uint2*)h;
    float a0 = 0.f, a1 = 0.f, a2 = 0.f, a3 = 0.f;
    for (int n = s; n < e; n++) {
        float w = exn[n];
        uint2 v = h2[(size_t)n * 128 + d4];
        a0 = fmaf(w, bflo(v.x), a0);
        a1 = fmaf(w, bfhi(v.x), a1);
        a2 = fmaf(w, bflo(v.y), a2);
        a3 = fmaf(w, bfhi(v.y), a3);
    }
    *(float4*)&partial[((size_t)(g * 4 + q)) * FINALD + d4 * 4] = make_float4(a0, a1, a2, a3);
}

// ======================== final heads ========================
__global__ __launch_bounds__(128) void final_kernel(const float* __restrict__ partial,
                                                    const float* __restrict__ gsum,
                                                    const float* __restrict__ Wmu,
                                                    const float* __restrict__ bmu,
                                                    const float* __restrict__ Wlv,
                                                    const float* __restrict__ blv,
                                                    float* __restrict__ out) {
    int g = blockIdx.x, j = threadIdx.x;
    const float* p = partial + (size_t)g * 4 * FINALD;
    float am = 0.f, av = 0.f;
    for (int k = 0; k < FINALD; k++) {
        float pv = p[k] + p[FINALD + k] + p[2 * FINALD + k] + p[3 * FINALD + k];
        am = fmaf(pv, Wmu[k * LATD + j], am);
        av = fmaf(pv, Wlv[k * LATD + j], av);
    }
    float inv = 1.f / fmaxf(gsum[g], 1e-9f);
    out[g * LATD + j] = am * inv + bmu[j];
    out[NGRAPH * LATD + g * LATD + j] = av * inv + blv[j];
}

// ======================== driver ========================
extern "C" void kernel_launch(void* const* d_in, const int* in_sizes, int n_in,
                              void* d_out, int out_size, void* d_ws, size_t ws_size,
                              hipStream_t stream) {
    (void)in_sizes; (void)n_in; (void)out_size; (void)ws_size;
    const float* node_feat = (const float*)d_in[0];
    const int* src = (const int*)d_in[1];
    const int* dst = (const int*)d_in[2];
    const int* gid = (const int*)d_in[3];
    const float* W[3]    = {(const float*)d_in[4],  (const float*)d_in[8],  (const float*)d_in[12]};
    const float* al[3]   = {(const float*)d_in[5],  (const float*)d_in[9],  (const float*)d_in[13]};
    const float* ar[3]   = {(const float*)d_in[6],  (const float*)d_in[10], (const float*)d_in[14]};
    const float* bias[3] = {(const float*)d_in[7],  (const float*)d_in[11], (const float*)d_in[15]};
    const float* Wg1 = (const float*)d_in[16];
    const float* bg1 = (const float*)d_in[17];
    const float* Wg2 = (const float*)d_in[18];
    const float* bg2 = (const float*)d_in[19];
    const float* Wmu = (const float*)d_in[20];
    const float* bmu = (const float*)d_in[21];
    const float* Wlv = (const float*)d_in[22];
    const float* blv = (const float*)d_in[23];

    // workspace ~230 MB (bf16 big buffers)
    char* ws = (char*)d_ws;
    size_t woff = 0;
    auto carve = [&](size_t bytes) {
        void* p = ws + woff;
        woff = (woff + bytes + 255) & ~(size_t)255;
        return p;
    };
    ushort* hA      = (ushort*)carve((size_t)NNODES * 512 * 2);  // aggregated h (bf16)
    ushort* hB      = (ushort*)carve((size_t)NNODES * 512 * 2);  // Wh (bf16); reused as fp32 hg
    float*  el      = (float*) carve((size_t)NNODES * 4 * 4);
    float*  er      = (float*) carve((size_t)NNODES * 4 * 4);
    float*  aw      = (float*) carve((size_t)NEDGES * 4 * 4);
    float*  nsum    = (float*) carve((size_t)NNODES * 4 * 4);
    int*    deg     = (int*)   carve((size_t)NNODES * 4);
    int*    off     = (int*)   carve((size_t)(NNODES + 1) * 4);
    int*    cursor  = (int*)   carve((size_t)NNODES * 4);
    int*    src_csr = (int*)   carve((size_t)NEDGES * 4);
    int*    bsum    = (int*)   carve((size_t)(NB_SCAN + 1) * 4);
    float*  gate    = (float*) carve((size_t)NNODES * 4);
    float*  exn     = (float*) carve((size_t)NNODES * 4);
    int*    gstart  = (int*)   carve((size_t)(NGRAPH + 1) * 4);
    float*  partial = (float*) carve((size_t)NGRAPH * 4 * FINALD * 4);
    float*  gsum    = (float*) carve((size_t)NGRAPH * 4);
    ushort* Bt1     = (ushort*)carve((size_t)128 * K1P * 2);  // W1^T bf16 [128][96]
    ushort* Bt2     = (ushort*)carve((size_t)256 * 128 * 2);  // W2^T bf16 [256][128]
    ushort* Bt3     = (ushort*)carve((size_t)512 * 256 * 2);  // W3^T bf16 [512][256]
    ushort* Btg     = (ushort*)carve((size_t)64 * 512 * 2);   // Wg1^T bf16 [64][512]
    float*  hg      = (float*)hB;   // Wh3 region dead once layer-3 aggregate done
    ushort* x0      = hA;           // alias: x0 dead before hA first written (L1 aggregate)

    // ---- CSR build + conversions ----
    zero_int_kernel<<<(NNODES + 255) / 256, 256, 0, stream>>>(deg, NNODES);
    count_kernel<<<(NEDGES + 255) / 256, 256, 0, stream>>>(dst, deg);
    scan_block_kernel<<<NB_SCAN, 1024, 0, stream>>>(deg, off, bsum);
    scan_bsum_kernel<<<1, 128, 0, stream>>>(bsum);
    scan_add_kernel<<<NB_SCAN, 1024, 0, stream>>>(off, bsum);
    copy_int_kernel<<<(NNODES + 255) / 256, 256, 0, stream>>>(off, cursor, NNODES);
    scatter_kernel<<<(NEDGES + 255) / 256, 256, 0, stream>>>(src, dst, cursor, src_csr);
    gstart_kernel<<<1, 128, 0, stream>>>(gid, gstart);
    wconv_pad_kernel<<<(128 * K1P + 255) / 256, 256, 0, stream>>>(W[0], Bt1, 92, K1P, 128);
    wconv_pad_kernel<<<(256 * 128 + 255) / 256, 256, 0, stream>>>(W[1], Bt2, 128, 128, 256);
    wconv_pad_kernel<<<(512 * 256 + 255) / 256, 256, 0, stream>>>(W[2], Bt3, 256, 256, 512);
    wconv_pad_kernel<<<(64 * 512 + 255) / 256, 256, 0, stream>>>(Wg1, Btg, 512, 512, 64);
    conv_x0_kernel<<<(NNODES * K1P + 255) / 256, 256, 0, stream>>>(node_feat, x0);

    const int HDs[3]     = {128, 256, 512};
    const int logHD16[3] = {3, 4, 5};
    const int logD[3]    = {5, 6, 7};
    const int MB = (NNODES + 127) / 128;  // 782

    for (int l = 0; l < 3; l++) {
        int HD = HDs[l];
        if (l == 0)
            mfma_gemm<128, false, ushort><<<dim3(MB, 1), 256, 0, stream>>>(
                x0, Bt1, nullptr, hB, NNODES, K1P, 128);
        else if (l == 1)
            mfma_gemm<128, false, ushort><<<dim3(MB, 2), 256, 0, stream>>>(
                hA, Bt2, nullptr, hB, NNODES, 128, 256);
        else
            mfma_gemm<128, false, ushort><<<dim3(MB, 4), 256, 0, stream>>>(
                hA, Bt3, nullptr, hB, NNODES, 256, 512);
        if (l == 0)      eler_node<128><<<NNODES / 4, 256, 0, stream>>>(hB, al[l], ar[l], el, er);
        else if (l == 1) eler_node<256><<<NNODES / 4, 256, 0, stream>>>(hB, al[l], ar[l], el, er);
        else             eler_node<512><<<NNODES / 4, 256, 0, stream>>>(hB, al[l], ar[l], el, er);
        attn_node<<<(NNODES + 255) / 256, 256, 0, stream>>>(
            src_csr, off, (const float4*)el, (const float4*)er, (float4*)aw, (float4*)nsum);
        int total16 = NNODES * (HD / 16);
        gat_aggregate16<<<(total16 + 255) / 256, 256, 0, stream>>>(
            src_csr, off, hB, aw, nsum, bias[l], hA, HD, logHD16[l], logD[l], total16);
    }

    // ---- attention pooling + heads ----
    mfma_gemm<64, true, float><<<dim3(MB, 1), 256, 0, stream>>>(
        hA, Btg, bg1, hg, NNODES, FINALD, HIDG);
    gate_dot<<<NNODES / 4, 256, 0, stream>>>(hg, Wg2, bg2, gate);
    graph_softmax_kernel<<<NGRAPH, 256, 0, stream>>>(gate, gstart, exn, gsum);
    pool_partial<<<dim3(NGRAPH, 4), 128, 0, stream>>>(hA, exn, gstart, partial);
    final_kernel<<<NGRAPH, 128, 0, stream>>>(partial, gsum, Wmu, bmu, Wlv, blv, (float*)d_out);
}